// Round 3
// baseline (240.378 us; speedup 1.0000x reference)
//
#include <hip/hip_runtime.h>
#include <hip/hip_bf16.h>

typedef __bf16 bf16x8 __attribute__((ext_vector_type(8)));
typedef float  f32x16 __attribute__((ext_vector_type(16)));
typedef float  f32x4  __attribute__((ext_vector_type(4)));

static constexpr int Bz = 2, Nn = 4096, Ee = 4, Dd = 64, ADim = 32;
static constexpr int Mm = Nn * Ee;  // 16384 reduction dim

__device__ __forceinline__ bf16x8 cvt8(float4 a, float4 b) {
  bf16x8 r;
  r[0] = (__bf16)a.x; r[1] = (__bf16)a.y; r[2] = (__bf16)a.z; r[3] = (__bf16)a.w;
  r[4] = (__bf16)b.x; r[5] = (__bf16)b.y; r[6] = (__bf16)b.z; r[7] = (__bf16)b.w;
  return r;
}
__device__ __forceinline__ f32x16 zero16() {
  f32x16 z;
#pragma unroll
  for (int i = 0; i < 16; ++i) z[i] = 0.f;
  return z;
}
__device__ __forceinline__ f32x4 zero4() {
  f32x4 z; z[0] = z[1] = z[2] = z[3] = 0.f; return z;
}
__device__ __forceinline__ f32x16 mm(bf16x8 a, bf16x8 b, f32x16 c) {
  return __builtin_amdgcn_mfma_f32_32x32x16_bf16(a, b, c, 0, 0, 0);
}
__device__ __forceinline__ f32x4 mm16(bf16x8 a, bf16x8 b, f32x4 c) {
  return __builtin_amdgcn_mfma_f32_16x16x32_bf16(a, b, c, 0, 0, 0);
}
__device__ __forceinline__ float sigm(float x) { return 1.f / (1.f + __expf(-x)); }
__device__ __forceinline__ float tanh_fast(float x) {
  float e = __expf(2.f * x);
  return 1.f - 2.f / (e + 1.f);
}

// -------- Kernel 0: pack GRU/head weights into bf16 MFMA B-fragments.
// frag f: 0..15 Wr, 16..31 Wz, 32..47 Wh, 48..59 Wo1. Within each: f = ks*2+oh.
// element j of lane l = W[32*oh + (l&31)][16*ks + 8*(l>>5) + j]
__global__ __launch_bounds__(64) void k_pack(
    const float* __restrict__ Wr, const float* __restrict__ Wz,
    const float* __restrict__ Wh, const float* __restrict__ Wo1,
    __bf16* __restrict__ Wp) {
  const int f = blockIdx.x, l = threadIdx.x;
  const int r31 = l & 31, h = l >> 5;
  const float* W; int L, fl;
  if (f < 16)      { W = Wr;  L = 128; fl = f; }
  else if (f < 32) { W = Wz;  L = 128; fl = f - 16; }
  else if (f < 48) { W = Wh;  L = 128; fl = f - 32; }
  else             { W = Wo1; L = 96;  fl = f - 48; }
  const int ks = fl >> 1, oh = fl & 1;
  const float* src = W + (size_t)(32 * oh + r31) * L + 16 * ks + 8 * h;
  float4 s0 = *reinterpret_cast<const float4*>(src);
  float4 s1 = *reinterpret_cast<const float4*>(src + 4);
  *reinterpret_cast<bf16x8*>(Wp + ((size_t)f * 64 + l) * 8) = cvt8(s0, s1);
}

// -------- Kernel 1: Bt[b][d][e*N+n] = sum_d' W_in[e][d][d'] * prop[b][n][d'] + b_in[e][d], bf16
__global__ __launch_bounds__(256) void k_build_bt(
    const float* __restrict__ prop, const float* __restrict__ Win,
    const float* __restrict__ bin, __bf16* __restrict__ Bt) {
  const int nchunk = blockIdx.x;          // 0..63  (64 n per block)
  const int e = blockIdx.y, b = blockIdx.z;
  const int tid = threadIdx.x;
  const int w = tid >> 6, l = tid & 63;
  const int r31 = l & 31, h = l >> 5;
  const int oh = w & 1, ns = w >> 1;
  const int o_row = oh * 32 + r31;                       // A-frag row (output dim)
  const int n_col = nchunk * 64 + ns * 32 + r31;         // B-frag col (node)
  const float* wbase = Win + ((size_t)e * 64 + o_row) * 64 + 8 * h;
  const float* pbase = prop + ((size_t)b * Nn + n_col) * 64 + 8 * h;
  f32x16 acc = zero16();
#pragma unroll
  for (int ks = 0; ks < 4; ++ks) {
    float4 w0 = *reinterpret_cast<const float4*>(wbase + 16 * ks);
    float4 w1 = *reinterpret_cast<const float4*>(wbase + 16 * ks + 4);
    float4 p0 = *reinterpret_cast<const float4*>(pbase + 16 * ks);
    float4 p1 = *reinterpret_cast<const float4*>(pbase + 16 * ks + 4);
    acc = mm(cvt8(w0, w1), cvt8(p0, p1), acc);
  }
#pragma unroll
  for (int reg = 0; reg < 16; ++reg) {
    int orow = oh * 32 + (reg & 3) + 8 * (reg >> 2) + 4 * h;
    float v = acc[reg] + bin[e * 64 + orow];
    Bt[((size_t)b * 64 + orow) * Mm + (size_t)e * Nn + n_col] = (__bf16)v;
  }
}

// -------- Kernel 2: a_in[b][n][d] = sum_m A[b][n][m] * Bt[b][d][m]
// 16x16x32 MFMA: A-frag reads 16 rows x 128 B contiguous per instruction.
// 512 blocks (16-row tiles), 8 waves split K 8-ways, LDS reduce.
__global__ __launch_bounds__(512, 4) void k_big_gemm(
    const float* __restrict__ A, const __bf16* __restrict__ Bt,
    float* __restrict__ a_in) {
  __shared__ float red[8][16][64];  // 32 KB
  const int bid = blockIdx.x;
  const int b = bid >> 8;            // 256 row-tiles per batch
  const int n0 = (bid & 255) * 16;
  const int tid = threadIdx.x;
  const int w = tid >> 6, l = tid & 63;
  const int r15 = l & 15, q = l >> 4;        // q in 0..3
  const size_t kstart = (size_t)w * 2048;    // K split 8 ways across waves

  const float* ap = A + ((size_t)b * Nn + (n0 + r15)) * Mm + kstart + 8 * q;
  const __bf16* bp = Bt + ((size_t)b * 64 + r15) * Mm + kstart + 8 * q;

  f32x4 acc0 = zero4(), acc1 = zero4(), acc2 = zero4(), acc3 = zero4();
#pragma unroll 2
  for (int s = 0; s < 64; ++s) {
    float4 a0 = *reinterpret_cast<const float4*>(ap);
    float4 a1 = *reinterpret_cast<const float4*>(ap + 4);
    bf16x8 fb0 = *reinterpret_cast<const bf16x8*>(bp);
    bf16x8 fb1 = *reinterpret_cast<const bf16x8*>(bp + (size_t)16 * Mm);
    bf16x8 fb2 = *reinterpret_cast<const bf16x8*>(bp + (size_t)32 * Mm);
    bf16x8 fb3 = *reinterpret_cast<const bf16x8*>(bp + (size_t)48 * Mm);
    bf16x8 fa = cvt8(a0, a1);
    acc0 = mm16(fa, fb0, acc0);
    acc1 = mm16(fa, fb1, acc1);
    acc2 = mm16(fa, fb2, acc2);
    acc3 = mm16(fa, fb3, acc3);
    ap += 32; bp += 32;
  }
  // C/D (16x16): col = lane&15, row = (lane>>4)*4 + reg
#pragma unroll
  for (int reg = 0; reg < 4; ++reg) {
    int row = q * 4 + reg;
    red[w][row][r15]      = acc0[reg];
    red[w][row][16 + r15] = acc1[reg];
    red[w][row][32 + r15] = acc2[reg];
    red[w][row][48 + r15] = acc3[reg];
  }
  __syncthreads();
  // reduce 8 wave-partials; 512 threads x 2 floats = 1024 outputs
  const int row = tid >> 5, col = (tid & 31) * 2;
  float s0 = 0.f, s1 = 0.f;
#pragma unroll
  for (int ww = 0; ww < 8; ++ww) {
    float2 v = *reinterpret_cast<const float2*>(&red[ww][row][col]);
    s0 += v.x; s1 += v.y;
  }
  float2 o; o.x = s0; o.y = s1;
  *reinterpret_cast<float2*>(a_in + ((size_t)(b * Nn + n0 + row)) * 64 + col) = o;
}

// -------- Kernel 3: GRU gate update + output head, 1 wave per 32 rows
__global__ __launch_bounds__(64) void k_gru(
    const float* __restrict__ a_in, const float* __restrict__ prop,
    const float* __restrict__ annot, const __bf16* __restrict__ Wp,
    const float* __restrict__ br, const float* __restrict__ bz,
    const float* __restrict__ bh, const float* __restrict__ bo1,
    const float* __restrict__ Wo2, const float* __restrict__ bo2,
    float* __restrict__ out) {
  __shared__ float plds[32][68];
  __shared__ float tlds[32][68];
  const int R0 = blockIdx.x * 32;  // flat row = b*N + n
  const int l = threadIdx.x;
  const int r31 = l & 31, h = l >> 5;

  // ---- load A-frags for X1 = [a_in | prop]; stash prop f32 tile into LDS
  bf16x8 xa[4], xp[4], xan[2];
  {
    const float* ab = a_in + (size_t)(R0 + r31) * 64 + 8 * h;
    const float* pb = prop + (size_t)(R0 + r31) * 64 + 8 * h;
#pragma unroll
    for (int ks = 0; ks < 4; ++ks) {
      float4 a0 = *reinterpret_cast<const float4*>(ab + 16 * ks);
      float4 a1 = *reinterpret_cast<const float4*>(ab + 16 * ks + 4);
      xa[ks] = cvt8(a0, a1);
      float4 p0 = *reinterpret_cast<const float4*>(pb + 16 * ks);
      float4 p1 = *reinterpret_cast<const float4*>(pb + 16 * ks + 4);
      xp[ks] = cvt8(p0, p1);
      *reinterpret_cast<float4*>(&plds[r31][16 * ks + 8 * h]) = p0;
      *reinterpret_cast<float4*>(&plds[r31][16 * ks + 8 * h + 4]) = p1;
    }
    const float* anb = annot + (size_t)(R0 + r31) * ADim + 8 * h;
#pragma unroll
    for (int ks = 0; ks < 2; ++ks) {
      float4 a0 = *reinterpret_cast<const float4*>(anb + 16 * ks);
      float4 a1 = *reinterpret_cast<const float4*>(anb + 16 * ks + 4);
      xan[ks] = cvt8(a0, a1);
    }
  }
  __syncthreads();

  // packed weight fragment load: 16B per lane, fragment-ordered bf16
#define LDWP(base, ks, oh) \
  (*reinterpret_cast<const bf16x8*>(Wp + (((size_t)(base) + (ks) * 2 + (oh)) * 64 + l) * 8))

  // ---- gates r, z : X1 @ {Wr,Wz}^T
  f32x16 aR[2] = {zero16(), zero16()}, aZ[2] = {zero16(), zero16()};
#pragma unroll
  for (int ks = 0; ks < 8; ++ks) {
    bf16x8 af = (ks < 4) ? xa[ks] : xp[ks - 4];
#pragma unroll
    for (int oh = 0; oh < 2; ++oh) {
      aR[oh] = mm(af, LDWP(0, ks, oh), aR[oh]);
      aZ[oh] = mm(af, LDWP(16, ks, oh), aZ[oh]);
    }
  }
  const float br_[2] = {br[r31], br[32 + r31]};
  const float bz_[2] = {bz[r31], bz[32 + r31]};
  float propv[2][16], zv[2][16];
#pragma unroll
  for (int oh = 0; oh < 2; ++oh) {
#pragma unroll
    for (int reg = 0; reg < 16; ++reg) {
      int row = (reg & 3) + 8 * (reg >> 2) + 4 * h;
      int o = 32 * oh + r31;
      propv[oh][reg] = plds[row][o];
      float rv = sigm(aR[oh][reg] + br_[oh]);
      zv[oh][reg] = sigm(aZ[oh][reg] + bz_[oh]);
      tlds[row][o] = rv * propv[oh][reg];  // r * prop, C/D layout -> LDS
    }
  }
  __syncthreads();
  bf16x8 xr[4];
#pragma unroll
  for (int ks = 0; ks < 4; ++ks) {
    float4 t0 = *reinterpret_cast<const float4*>(&tlds[r31][16 * ks + 8 * h]);
    float4 t1 = *reinterpret_cast<const float4*>(&tlds[r31][16 * ks + 8 * h + 4]);
    xr[ks] = cvt8(t0, t1);
  }
  // ---- candidate h_hat : [a_in | r*prop] @ Wh^T
  f32x16 aH[2] = {zero16(), zero16()};
#pragma unroll
  for (int ks = 0; ks < 8; ++ks) {
    bf16x8 af = (ks < 4) ? xa[ks] : xr[ks - 4];
#pragma unroll
    for (int oh = 0; oh < 2; ++oh) aH[oh] = mm(af, LDWP(32, ks, oh), aH[oh]);
  }
  __syncthreads();  // xr reads done before tlds overwrite
  const float bh_[2] = {bh[r31], bh[32 + r31]};
#pragma unroll
  for (int oh = 0; oh < 2; ++oh) {
#pragma unroll
    for (int reg = 0; reg < 16; ++reg) {
      int row = (reg & 3) + 8 * (reg >> 2) + 4 * h;
      int o = 32 * oh + r31;
      float hh = tanh_fast(aH[oh][reg] + bh_[oh]);
      float z = zv[oh][reg];
      tlds[row][o] = (1.f - z) * propv[oh][reg] + z * hh;  // new_state
    }
  }
  __syncthreads();
  bf16x8 xn[4];
#pragma unroll
  for (int ks = 0; ks < 4; ++ks) {
    float4 t0 = *reinterpret_cast<const float4*>(&tlds[r31][16 * ks + 8 * h]);
    float4 t1 = *reinterpret_cast<const float4*>(&tlds[r31][16 * ks + 8 * h + 4]);
    xn[ks] = cvt8(t0, t1);
  }
  // ---- output head: h = tanh([new | annot] @ Wo1^T + bo1); out = h @ Wo2^T + bo2
  f32x16 aO[2] = {zero16(), zero16()};
#pragma unroll
  for (int ks = 0; ks < 6; ++ks) {
    bf16x8 af = (ks < 4) ? xn[ks] : xan[ks - 4];
#pragma unroll
    for (int oh = 0; oh < 2; ++oh) aO[oh] = mm(af, LDWP(48, ks, oh), aO[oh]);
  }
  const float bo1_[2] = {bo1[r31], bo1[32 + r31]};
  const float wo2_[2] = {Wo2[r31], Wo2[32 + r31]};
  const float bo2v = bo2[0];
#pragma unroll
  for (int reg = 0; reg < 16; ++reg) {
    float h0 = tanh_fast(aO[0][reg] + bo1_[0]);
    float h1 = tanh_fast(aO[1][reg] + bo1_[1]);
    float p = h0 * wo2_[0] + h1 * wo2_[1];
#pragma unroll
    for (int mks = 16; mks >= 1; mks >>= 1) p += __shfl_xor(p, mks, 64);
    if (r31 == 0) {
      int row = (reg & 3) + 8 * (reg >> 2) + 4 * h;
      out[R0 + row] = p + bo2v;
    }
  }
#undef LDWP
}

extern "C" void kernel_launch(void* const* d_in, const int* in_sizes, int n_in,
                              void* d_out, int out_size, void* d_ws, size_t ws_size,
                              hipStream_t stream) {
  const float* prop  = (const float*)d_in[0];
  const float* annot = (const float*)d_in[1];
  const float* A     = (const float*)d_in[2];
  const float* Win   = (const float*)d_in[3];
  const float* bin   = (const float*)d_in[4];
  const float* Wr    = (const float*)d_in[5];
  const float* br    = (const float*)d_in[6];
  const float* Wz    = (const float*)d_in[7];
  const float* bz    = (const float*)d_in[8];
  const float* Wh    = (const float*)d_in[9];
  const float* bh    = (const float*)d_in[10];
  const float* Wo1   = (const float*)d_in[11];
  const float* bo1   = (const float*)d_in[12];
  const float* Wo2   = (const float*)d_in[13];
  const float* bo2   = (const float*)d_in[14];
  float* out = (float*)d_out;

  char* ws = (char*)d_ws;
  __bf16* Bt   = (__bf16*)ws;                                    // [B][64][16384] bf16 = 4 MB
  float*  a_in = (float*)(ws + (size_t)Bz * Dd * Mm * 2);        // [B][N][64] f32 = 2 MB
  __bf16* Wp   = (__bf16*)(ws + (size_t)Bz * Dd * Mm * 2 + (size_t)Bz * Nn * Dd * 4);  // 60 KB

  k_pack<<<dim3(60), 64, 0, stream>>>(Wr, Wz, Wh, Wo1, Wp);
  k_build_bt<<<dim3(Nn / 64, Ee, Bz), 256, 0, stream>>>(prop, Win, bin, Bt);
  k_big_gemm<<<dim3(Bz * (Nn / 16)), 512, 0, stream>>>(A, Bt, a_in);
  k_gru<<<dim3(Bz * Nn / 32), 64, 0, stream>>>(a_in, prop, annot, Wp,
                                               br, bz, bh, bo1, Wo2, bo2, out);
}

// Round 4
// 200.979 us; speedup vs baseline: 1.1960x; 1.1960x over previous
//
#include <hip/hip_runtime.h>
#include <hip/hip_bf16.h>
#include <stdint.h>

typedef __bf16 bf16x8 __attribute__((ext_vector_type(8)));
typedef float  f32x16 __attribute__((ext_vector_type(16)));
typedef float  f32x4  __attribute__((ext_vector_type(4)));

static constexpr int Bz = 2, Nn = 4096, Ee = 4, Dd = 64, ADim = 32;
static constexpr int Mm = Nn * Ee;  // 16384 reduction dim

__device__ __forceinline__ bf16x8 cvt8(float4 a, float4 b) {
  bf16x8 r;
  r[0] = (__bf16)a.x; r[1] = (__bf16)a.y; r[2] = (__bf16)a.z; r[3] = (__bf16)a.w;
  r[4] = (__bf16)b.x; r[5] = (__bf16)b.y; r[6] = (__bf16)b.z; r[7] = (__bf16)b.w;
  return r;
}
__device__ __forceinline__ bf16x8 cvt8v(f32x4 a, f32x4 b) {
  bf16x8 r;
  r[0] = (__bf16)a[0]; r[1] = (__bf16)a[1]; r[2] = (__bf16)a[2]; r[3] = (__bf16)a[3];
  r[4] = (__bf16)b[0]; r[5] = (__bf16)b[1]; r[6] = (__bf16)b[2]; r[7] = (__bf16)b[3];
  return r;
}
__device__ __forceinline__ f32x16 zero16() {
  f32x16 z;
#pragma unroll
  for (int i = 0; i < 16; ++i) z[i] = 0.f;
  return z;
}
__device__ __forceinline__ f32x16 mm(bf16x8 a, bf16x8 b, f32x16 c) {
  return __builtin_amdgcn_mfma_f32_32x32x16_bf16(a, b, c, 0, 0, 0);
}
__device__ __forceinline__ float sigm(float x) { return 1.f / (1.f + __expf(-x)); }
__device__ __forceinline__ float tanh_fast(float x) {
  float e = __expf(2.f * x);
  return 1.f - 2.f / (e + 1.f);
}
__device__ __forceinline__ void async_lds16(const void* g, void* l) {
  __builtin_amdgcn_global_load_lds(
      (const __attribute__((address_space(1))) uint32_t*)g,
      (__attribute__((address_space(3))) uint32_t*)l, 16, 0, 0);
}

// -------- Kernel 0: pack GRU/head weights into bf16 MFMA B-fragments.
__global__ __launch_bounds__(64) void k_pack(
    const float* __restrict__ Wr, const float* __restrict__ Wz,
    const float* __restrict__ Wh, const float* __restrict__ Wo1,
    __bf16* __restrict__ Wp) {
  const int f = blockIdx.x, l = threadIdx.x;
  const int r31 = l & 31, h = l >> 5;
  const float* W; int L, fl;
  if (f < 16)      { W = Wr;  L = 128; fl = f; }
  else if (f < 32) { W = Wz;  L = 128; fl = f - 16; }
  else if (f < 48) { W = Wh;  L = 128; fl = f - 32; }
  else             { W = Wo1; L = 96;  fl = f - 48; }
  const int ks = fl >> 1, oh = fl & 1;
  const float* src = W + (size_t)(32 * oh + r31) * L + 16 * ks + 8 * h;
  float4 s0 = *reinterpret_cast<const float4*>(src);
  float4 s1 = *reinterpret_cast<const float4*>(src + 4);
  *reinterpret_cast<bf16x8*>(Wp + ((size_t)f * 64 + l) * 8) = cvt8(s0, s1);
}

// -------- Kernel 1: Bt[b][d][e*N+n] = sum_d' W_in[e][d][d'] * prop[b][n][d'] + b_in[e][d]
__global__ __launch_bounds__(256) void k_build_bt(
    const float* __restrict__ prop, const float* __restrict__ Win,
    const float* __restrict__ bin, __bf16* __restrict__ Bt) {
  const int nchunk = blockIdx.x;
  const int e = blockIdx.y, b = blockIdx.z;
  const int tid = threadIdx.x;
  const int w = tid >> 6, l = tid & 63;
  const int r31 = l & 31, h = l >> 5;
  const int oh = w & 1, ns = w >> 1;
  const int o_row = oh * 32 + r31;
  const int n_col = nchunk * 64 + ns * 32 + r31;
  const float* wbase = Win + ((size_t)e * 64 + o_row) * 64 + 8 * h;
  const float* pbase = prop + ((size_t)b * Nn + n_col) * 64 + 8 * h;
  f32x16 acc = zero16();
#pragma unroll
  for (int ks = 0; ks < 4; ++ks) {
    float4 w0 = *reinterpret_cast<const float4*>(wbase + 16 * ks);
    float4 w1 = *reinterpret_cast<const float4*>(wbase + 16 * ks + 4);
    float4 p0 = *reinterpret_cast<const float4*>(pbase + 16 * ks);
    float4 p1 = *reinterpret_cast<const float4*>(pbase + 16 * ks + 4);
    acc = mm(cvt8(w0, w1), cvt8(p0, p1), acc);
  }
#pragma unroll
  for (int reg = 0; reg < 16; ++reg) {
    int orow = oh * 32 + (reg & 3) + 8 * (reg >> 2) + 4 * h;
    float v = acc[reg] + bin[e * 64 + orow];
    Bt[((size_t)b * 64 + orow) * Mm + (size_t)e * Nn + n_col] = (__bf16)v;
  }
}

// -------- Kernel 2: a_in[b][n][d] = sum_m A[b][n][m] * Bt[b][d][m]
// 1 block/CU, 8 waves, per-wave K-split (2048 each) with private LDS
// double-buffer filled by global_load_lds (coalesced 1KB/issue), counted
// vmcnt pipeline, NO barriers in the K-loop. XOR source-swizzle (u^=row&7)
// so ds_read_b128 fragments are ~4-way instead of 32-way conflicted.
__global__ __launch_bounds__(512, 2) void k_big_gemm(
    const float* __restrict__ A, const __bf16* __restrict__ Bt,
    float* __restrict__ a_in) {
  __shared__ union {
    float stage[8][2][32][32];  // [wave][buf][row][32 f32]  = 64 KB
    float red[8][32][64];       // epilogue alias: red[w] == wave w's stage
  } smem;

  const int bid = blockIdx.x;                       // 0..255
  const int tile = (bid & 7) * 32 + (bid >> 3);     // XCD-contiguous map
  const int b = tile >> 7;
  const int n0 = (tile & 127) * 32;
  const int tid = threadIdx.x;
  const int w = tid >> 6, l = tid & 63;
  const int r31 = l & 31, h = l >> 5;
  const size_t kw = (size_t)w * 2048;               // wave K start

  const float* Ab = A + ((size_t)b * Nn + n0) * Mm + kw;
  const __bf16* Bp = Bt + ((size_t)b * 64 + r31) * (size_t)Mm + kw + 8 * h;

  const int srow = l >> 3;       // 0..7: row-in-group for staging
  const int umem = l & 7;        // 16B-unit slot in LDS row
  float* sbase = &smem.stage[w][0][0][0];

  // stage chunk c (32 f32 per row, 32 rows) into buffer p: 4 issues of 1 KB
#define STAGE(c, p)                                                        \
  {                                                                        \
    const float* gk_ = Ab + (c) * 32;                                      \
    _Pragma("unroll")                                                      \
    for (int j_ = 0; j_ < 4; ++j_) {                                       \
      int row_ = 8 * j_ + srow;                                            \
      int ug_ = umem ^ (row_ & 7);                                         \
      const float* gp_ = gk_ + (size_t)row_ * Mm + ug_ * 4;                \
      char* lp_ = (char*)sbase + (p) * 4096 + j_ * 1024;                   \
      async_lds16(gp_, lp_);                                               \
    }                                                                      \
  }

  f32x16 acc0 = zero16(), acc1 = zero16();
  STAGE(0, 0);
  STAGE(1, 1);

#pragma unroll 2
  for (int i = 0; i < 64; ++i) {
    // all but the 4 youngest VMEM ops retired => chunk i staged, fb(i-1) done
    asm volatile("s_waitcnt vmcnt(4)" ::: "memory");
    const int p = i & 1;
    const float* sb = sbase + p * 1024;  // floats
#pragma unroll
    for (int k = 0; k < 2; ++k) {
      const int u0 = 4 * k + 2 * h;
      f32x4 fa0 = *reinterpret_cast<const f32x4*>(sb + r31 * 32 + ((u0 ^ (r31 & 7)) * 4));
      f32x4 fa1 = *reinterpret_cast<const f32x4*>(sb + r31 * 32 + (((u0 + 1) ^ (r31 & 7)) * 4));
      bf16x8 fb0 = *reinterpret_cast<const bf16x8*>(Bp + (size_t)i * 32 + k * 16);
      bf16x8 fb1 = *reinterpret_cast<const bf16x8*>(Bp + (size_t)32 * Mm + (size_t)i * 32 + k * 16);
      bf16x8 fa = cvt8v(fa0, fa1);
      acc0 = mm(fa, fb0, acc0);
      acc1 = mm(fa, fb1, acc1);
    }
    // ds_reads of buf p drained before we overwrite it with chunk i+2
    asm volatile("s_waitcnt lgkmcnt(0)" ::: "memory");
    if (i + 2 < 64) STAGE(i + 2, p);
  }
#undef STAGE

  // epilogue: red[w] aliases wave w's own staging region — safe pre-barrier
#pragma unroll
  for (int reg = 0; reg < 16; ++reg) {
    int row = (reg & 3) + 8 * (reg >> 2) + 4 * h;
    smem.red[w][row][r31] = acc0[reg];
    smem.red[w][row][32 + r31] = acc1[reg];
  }
  __syncthreads();
  const int rr = tid >> 4;           // 0..31
  const int cc = (tid & 15) * 4;     // 0..60
  f32x4 s; s[0] = s[1] = s[2] = s[3] = 0.f;
#pragma unroll
  for (int ww = 0; ww < 8; ++ww) {
    f32x4 v = *reinterpret_cast<const f32x4*>(&smem.red[ww][rr][cc]);
    s[0] += v[0]; s[1] += v[1]; s[2] += v[2]; s[3] += v[3];
  }
  *reinterpret_cast<f32x4*>(a_in + ((size_t)(b * Nn + n0 + rr)) * 64 + cc) = s;
}

// -------- Kernel 3: GRU gate update + output head, 1 wave per 32 rows
__global__ __launch_bounds__(64) void k_gru(
    const float* __restrict__ a_in, const float* __restrict__ prop,
    const float* __restrict__ annot, const __bf16* __restrict__ Wp,
    const float* __restrict__ br, const float* __restrict__ bz,
    const float* __restrict__ bh, const float* __restrict__ bo1,
    const float* __restrict__ Wo2, const float* __restrict__ bo2,
    float* __restrict__ out) {
  __shared__ float plds[32][68];
  __shared__ float tlds[32][68];
  const int R0 = blockIdx.x * 32;
  const int l = threadIdx.x;
  const int r31 = l & 31, h = l >> 5;

  bf16x8 xa[4], xp[4], xan[2];
  {
    const float* ab = a_in + (size_t)(R0 + r31) * 64 + 8 * h;
    const float* pb = prop + (size_t)(R0 + r31) * 64 + 8 * h;
#pragma unroll
    for (int ks = 0; ks < 4; ++ks) {
      float4 a0 = *reinterpret_cast<const float4*>(ab + 16 * ks);
      float4 a1 = *reinterpret_cast<const float4*>(ab + 16 * ks + 4);
      xa[ks] = cvt8(a0, a1);
      float4 p0 = *reinterpret_cast<const float4*>(pb + 16 * ks);
      float4 p1 = *reinterpret_cast<const float4*>(pb + 16 * ks + 4);
      xp[ks] = cvt8(p0, p1);
      *reinterpret_cast<float4*>(&plds[r31][16 * ks + 8 * h]) = p0;
      *reinterpret_cast<float4*>(&plds[r31][16 * ks + 8 * h + 4]) = p1;
    }
    const float* anb = annot + (size_t)(R0 + r31) * ADim + 8 * h;
#pragma unroll
    for (int ks = 0; ks < 2; ++ks) {
      float4 a0 = *reinterpret_cast<const float4*>(anb + 16 * ks);
      float4 a1 = *reinterpret_cast<const float4*>(anb + 16 * ks + 4);
      xan[ks] = cvt8(a0, a1);
    }
  }
  __syncthreads();

#define LDWP(base, ks, oh) \
  (*reinterpret_cast<const bf16x8*>(Wp + (((size_t)(base) + (ks) * 2 + (oh)) * 64 + l) * 8))

  f32x16 aR[2] = {zero16(), zero16()}, aZ[2] = {zero16(), zero16()};
#pragma unroll
  for (int ks = 0; ks < 8; ++ks) {
    bf16x8 af = (ks < 4) ? xa[ks] : xp[ks - 4];
#pragma unroll
    for (int oh = 0; oh < 2; ++oh) {
      aR[oh] = mm(af, LDWP(0, ks, oh), aR[oh]);
      aZ[oh] = mm(af, LDWP(16, ks, oh), aZ[oh]);
    }
  }
  const float br_[2] = {br[r31], br[32 + r31]};
  const float bz_[2] = {bz[r31], bz[32 + r31]};
  float propv[2][16], zv[2][16];
#pragma unroll
  for (int oh = 0; oh < 2; ++oh) {
#pragma unroll
    for (int reg = 0; reg < 16; ++reg) {
      int row = (reg & 3) + 8 * (reg >> 2) + 4 * h;
      int o = 32 * oh + r31;
      propv[oh][reg] = plds[row][o];
      float rv = sigm(aR[oh][reg] + br_[oh]);
      zv[oh][reg] = sigm(aZ[oh][reg] + bz_[oh]);
      tlds[row][o] = rv * propv[oh][reg];
    }
  }
  __syncthreads();
  bf16x8 xr[4];
#pragma unroll
  for (int ks = 0; ks < 4; ++ks) {
    float4 t0 = *reinterpret_cast<const float4*>(&tlds[r31][16 * ks + 8 * h]);
    float4 t1 = *reinterpret_cast<const float4*>(&tlds[r31][16 * ks + 8 * h + 4]);
    xr[ks] = cvt8(t0, t1);
  }
  f32x16 aH[2] = {zero16(), zero16()};
#pragma unroll
  for (int ks = 0; ks < 8; ++ks) {
    bf16x8 af = (ks < 4) ? xa[ks] : xr[ks - 4];
#pragma unroll
    for (int oh = 0; oh < 2; ++oh) aH[oh] = mm(af, LDWP(32, ks, oh), aH[oh]);
  }
  __syncthreads();
  const float bh_[2] = {bh[r31], bh[32 + r31]};
#pragma unroll
  for (int oh = 0; oh < 2; ++oh) {
#pragma unroll
    for (int reg = 0; reg < 16; ++reg) {
      int row = (reg & 3) + 8 * (reg >> 2) + 4 * h;
      int o = 32 * oh + r31;
      float hh = tanh_fast(aH[oh][reg] + bh_[oh]);
      float z = zv[oh][reg];
      tlds[row][o] = (1.f - z) * propv[oh][reg] + z * hh;
    }
  }
  __syncthreads();
  bf16x8 xn[4];
#pragma unroll
  for (int ks = 0; ks < 4; ++ks) {
    float4 t0 = *reinterpret_cast<const float4*>(&tlds[r31][16 * ks + 8 * h]);
    float4 t1 = *reinterpret_cast<const float4*>(&tlds[r31][16 * ks + 8 * h + 4]);
    xn[ks] = cvt8(t0, t1);
  }
  f32x16 aO[2] = {zero16(), zero16()};
#pragma unroll
  for (int ks = 0; ks < 6; ++ks) {
    bf16x8 af = (ks < 4) ? xn[ks] : xan[ks - 4];
#pragma unroll
    for (int oh = 0; oh < 2; ++oh) aO[oh] = mm(af, LDWP(48, ks, oh), aO[oh]);
  }
  const float bo1_[2] = {bo1[r31], bo1[32 + r31]};
  const float wo2_[2] = {Wo2[r31], Wo2[32 + r31]};
  const float bo2v = bo2[0];
#pragma unroll
  for (int reg = 0; reg < 16; ++reg) {
    float h0 = tanh_fast(aO[0][reg] + bo1_[0]);
    float h1 = tanh_fast(aO[1][reg] + bo1_[1]);
    float p = h0 * wo2_[0] + h1 * wo2_[1];
#pragma unroll
    for (int mks = 16; mks >= 1; mks >>= 1) p += __shfl_xor(p, mks, 64);
    if (r31 == 0) {
      int row = (reg & 3) + 8 * (reg >> 2) + 4 * h;
      out[R0 + row] = p + bo2v;
    }
  }
#undef LDWP
}

extern "C" void kernel_launch(void* const* d_in, const int* in_sizes, int n_in,
                              void* d_out, int out_size, void* d_ws, size_t ws_size,
                              hipStream_t stream) {
  const float* prop  = (const float*)d_in[0];
  const float* annot = (const float*)d_in[1];
  const float* A     = (const float*)d_in[2];
  const float* Win   = (const float*)d_in[3];
  const float* bin   = (const float*)d_in[4];
  const float* Wr    = (const float*)d_in[5];
  const float* br    = (const float*)d_in[6];
  const float* Wz    = (const float*)d_in[7];
  const float* bz    = (const float*)d_in[8];
  const float* Wh    = (const float*)d_in[9];
  const float* bh    = (const float*)d_in[10];
  const float* Wo1   = (const float*)d_in[11];
  const float* bo1   = (const float*)d_in[12];
  const float* Wo2   = (const float*)d_in[13];
  const float* bo2   = (const float*)d_in[14];
  float* out = (float*)d_out;

  char* ws = (char*)d_ws;
  __bf16* Bt   = (__bf16*)ws;                                    // 4 MB
  float*  a_in = (float*)(ws + (size_t)Bz * Dd * Mm * 2);        // 2 MB
  __bf16* Wp   = (__bf16*)(ws + (size_t)Bz * Dd * Mm * 2 + (size_t)Bz * Nn * Dd * 4);  // 60 KB

  k_pack<<<dim3(60), 64, 0, stream>>>(Wr, Wz, Wh, Wo1, Wp);
  k_build_bt<<<dim3(Nn / 64, Ee, Bz), 256, 0, stream>>>(prop, Win, bin, Bt);
  k_big_gemm<<<dim3(256), 512, 0, stream>>>(A, Bt, a_in);
  k_gru<<<dim3(Bz * Nn / 32), 64, 0, stream>>>(a_in, prop, annot, Wp,
                                               br, bz, bh, bo1, Wo2, bo2, out);
}

// Round 5
// 196.020 us; speedup vs baseline: 1.2263x; 1.0253x over previous
//
#include <hip/hip_runtime.h>
#include <hip/hip_bf16.h>
#include <stdint.h>

typedef __bf16 bf16x8 __attribute__((ext_vector_type(8)));
typedef float  f32x16 __attribute__((ext_vector_type(16)));
typedef float  f32x4  __attribute__((ext_vector_type(4)));

static constexpr int Bz = 2, Nn = 4096, Ee = 4, Dd = 64, ADim = 32;
static constexpr int Mm = Nn * Ee;        // 16384 reduction dim
static constexpr int KSEG = 8;            // K-segments == XCD count
static constexpr int KLEN = Mm / KSEG;    // 2048 k per segment
static constexpr int NT = Bz * Nn / 32;   // 256 output row-tiles
static constexpr size_t SEGSTRIDE = (size_t)NT * 32 * 64;  // floats per kseg partial

__device__ __forceinline__ bf16x8 cvt8(float4 a, float4 b) {
  bf16x8 r;
  r[0] = (__bf16)a.x; r[1] = (__bf16)a.y; r[2] = (__bf16)a.z; r[3] = (__bf16)a.w;
  r[4] = (__bf16)b.x; r[5] = (__bf16)b.y; r[6] = (__bf16)b.z; r[7] = (__bf16)b.w;
  return r;
}
__device__ __forceinline__ bf16x8 cvt8v(f32x4 a, f32x4 b) {
  bf16x8 r;
  r[0] = (__bf16)a[0]; r[1] = (__bf16)a[1]; r[2] = (__bf16)a[2]; r[3] = (__bf16)a[3];
  r[4] = (__bf16)b[0]; r[5] = (__bf16)b[1]; r[6] = (__bf16)b[2]; r[7] = (__bf16)b[3];
  return r;
}
__device__ __forceinline__ f32x16 zero16() {
  f32x16 z;
#pragma unroll
  for (int i = 0; i < 16; ++i) z[i] = 0.f;
  return z;
}
__device__ __forceinline__ f32x16 mm(bf16x8 a, bf16x8 b, f32x16 c) {
  return __builtin_amdgcn_mfma_f32_32x32x16_bf16(a, b, c, 0, 0, 0);
}
__device__ __forceinline__ float sigm(float x) { return 1.f / (1.f + __expf(-x)); }
__device__ __forceinline__ float tanh_fast(float x) {
  float e = __expf(2.f * x);
  return 1.f - 2.f / (e + 1.f);
}

// -------- Kernel 0: pack GRU/head weights into bf16 MFMA B-fragments.
__global__ __launch_bounds__(64) void k_pack(
    const float* __restrict__ Wr, const float* __restrict__ Wz,
    const float* __restrict__ Wh, const float* __restrict__ Wo1,
    __bf16* __restrict__ Wp) {
  const int f = blockIdx.x, l = threadIdx.x;
  const int r31 = l & 31, h = l >> 5;
  const float* W; int L, fl;
  if (f < 16)      { W = Wr;  L = 128; fl = f; }
  else if (f < 32) { W = Wz;  L = 128; fl = f - 16; }
  else if (f < 48) { W = Wh;  L = 128; fl = f - 32; }
  else             { W = Wo1; L = 96;  fl = f - 48; }
  const int ks = fl >> 1, oh = fl & 1;
  const float* src = W + (size_t)(32 * oh + r31) * L + 16 * ks + 8 * h;
  float4 s0 = *reinterpret_cast<const float4*>(src);
  float4 s1 = *reinterpret_cast<const float4*>(src + 4);
  *reinterpret_cast<bf16x8*>(Wp + ((size_t)f * 64 + l) * 8) = cvt8(s0, s1);
}

// -------- Kernel 1: Bt[b][d][e*N+n] = sum_d' W_in[e][d][d'] * prop[b][n][d'] + b_in[e][d]
__global__ __launch_bounds__(256) void k_build_bt(
    const float* __restrict__ prop, const float* __restrict__ Win,
    const float* __restrict__ bin, __bf16* __restrict__ Bt) {
  const int nchunk = blockIdx.x;
  const int e = blockIdx.y, b = blockIdx.z;
  const int tid = threadIdx.x;
  const int w = tid >> 6, l = tid & 63;
  const int r31 = l & 31, h = l >> 5;
  const int oh = w & 1, ns = w >> 1;
  const int o_row = oh * 32 + r31;
  const int n_col = nchunk * 64 + ns * 32 + r31;
  const float* wbase = Win + ((size_t)e * 64 + o_row) * 64 + 8 * h;
  const float* pbase = prop + ((size_t)b * Nn + n_col) * 64 + 8 * h;
  f32x16 acc = zero16();
#pragma unroll
  for (int ks = 0; ks < 4; ++ks) {
    float4 w0 = *reinterpret_cast<const float4*>(wbase + 16 * ks);
    float4 w1 = *reinterpret_cast<const float4*>(wbase + 16 * ks + 4);
    float4 p0 = *reinterpret_cast<const float4*>(pbase + 16 * ks);
    float4 p1 = *reinterpret_cast<const float4*>(pbase + 16 * ks + 4);
    acc = mm(cvt8(w0, w1), cvt8(p0, p1), acc);
  }
#pragma unroll
  for (int reg = 0; reg < 16; ++reg) {
    int orow = oh * 32 + (reg & 3) + 8 * (reg >> 2) + 4 * h;
    float v = acc[reg] + bin[e * 64 + orow];
    Bt[((size_t)b * 64 + orow) * Mm + (size_t)e * Nn + n_col] = (__bf16)v;
  }
}

// -------- Kernel 2: split-K GEMM. part[kseg][tile][n][d] = sum_{m in seg} A*Bt.
// kseg = bid % 8 pins each K-segment to one XCD (round-robin dispatch), so the
// per-XCD Bt working set is 512 KB -> L2-resident; A is streamed exactly once.
__global__ __launch_bounds__(512, 2) void k_big_gemm(
    const float* __restrict__ A, const __bf16* __restrict__ Bt,
    float* __restrict__ part) {
  __shared__ float red[8][32][64];  // 64 KB
  const int bid = blockIdx.x;       // 0..2047
  const int kseg = bid & 7;         // == XCD under round-robin dispatch
  const int tile = bid >> 3;        // 0..255
  const int b = tile >> 7;
  const int n0 = (tile & 127) * 32;
  const int tid = threadIdx.x;
  const int w = tid >> 6, l = tid & 63;
  const int r31 = l & 31, h = l >> 5;
  const size_t k0 = (size_t)kseg * KLEN + w * (KLEN / 8);  // 256 k per wave

  const float* ap = A + ((size_t)b * Nn + (n0 + r31)) * Mm + k0 + 8 * h;
  const __bf16* bp = Bt + ((size_t)b * 64 + r31) * (size_t)Mm + k0 + 8 * h;

  f32x16 acc0 = zero16(), acc1 = zero16();
#pragma unroll 8
  for (int s = 0; s < 16; ++s) {
    float4 a0 = *reinterpret_cast<const float4*>(ap);
    float4 a1 = *reinterpret_cast<const float4*>(ap + 4);
    bf16x8 fb0 = *reinterpret_cast<const bf16x8*>(bp);
    bf16x8 fb1 = *reinterpret_cast<const bf16x8*>(bp + (size_t)32 * Mm);
    bf16x8 fa = cvt8(a0, a1);
    acc0 = mm(fa, fb0, acc0);
    acc1 = mm(fa, fb1, acc1);
    ap += 16; bp += 16;
  }
  // C/D (32x32): col = lane&31, row = (reg&3) + 8*(reg>>2) + 4*(lane>>5)
#pragma unroll
  for (int reg = 0; reg < 16; ++reg) {
    int row = (reg & 3) + 8 * (reg >> 2) + 4 * h;
    red[w][row][r31] = acc0[reg];
    red[w][row][32 + r31] = acc1[reg];
  }
  __syncthreads();
  const int rr = tid >> 4;           // 0..31
  const int cc = (tid & 15) * 4;     // 0..60
  f32x4 s; s[0] = s[1] = s[2] = s[3] = 0.f;
#pragma unroll
  for (int ww = 0; ww < 8; ++ww) {
    f32x4 v = *reinterpret_cast<const f32x4*>(&red[ww][rr][cc]);
    s[0] += v[0]; s[1] += v[1]; s[2] += v[2]; s[3] += v[3];
  }
  *reinterpret_cast<f32x4*>(part + (size_t)kseg * SEGSTRIDE +
                            ((size_t)tile * 32 + rr) * 64 + cc) = s;
}

// -------- Kernel 3: fold split-K reduce + GRU gate update + output head.
__global__ __launch_bounds__(64) void k_gru(
    const float* __restrict__ part, const float* __restrict__ prop,
    const float* __restrict__ annot, const __bf16* __restrict__ Wp,
    const float* __restrict__ br, const float* __restrict__ bz,
    const float* __restrict__ bh, const float* __restrict__ bo1,
    const float* __restrict__ Wo2, const float* __restrict__ bo2,
    float* __restrict__ out) {
  __shared__ float plds[32][68];
  __shared__ float tlds[32][68];
  const int tile = blockIdx.x;      // == k2's tile index
  const int R0 = tile * 32;         // flat row = b*N + n
  const int l = threadIdx.x;
  const int r31 = l & 31, h = l >> 5;

  bf16x8 xa[4], xp[4], xan[2];
  {
    // a_in tile = sum over 8 k-segment partials
    const float* pt = part + ((size_t)tile * 32 + r31) * 64 + 8 * h;
    const float* pb = prop + (size_t)(R0 + r31) * 64 + 8 * h;
#pragma unroll
    for (int ks = 0; ks < 4; ++ks) {
      f32x4 s0, s1;
      s0[0] = s0[1] = s0[2] = s0[3] = 0.f;
      s1[0] = s1[1] = s1[2] = s1[3] = 0.f;
#pragma unroll
      for (int seg = 0; seg < 8; ++seg) {
        const float* pp = pt + seg * SEGSTRIDE + 16 * ks;
        f32x4 v0 = *reinterpret_cast<const f32x4*>(pp);
        f32x4 v1 = *reinterpret_cast<const f32x4*>(pp + 4);
        s0[0] += v0[0]; s0[1] += v0[1]; s0[2] += v0[2]; s0[3] += v0[3];
        s1[0] += v1[0]; s1[1] += v1[1]; s1[2] += v1[2]; s1[3] += v1[3];
      }
      xa[ks] = cvt8v(s0, s1);
      float4 p0 = *reinterpret_cast<const float4*>(pb + 16 * ks);
      float4 p1 = *reinterpret_cast<const float4*>(pb + 16 * ks + 4);
      xp[ks] = cvt8(p0, p1);
      *reinterpret_cast<float4*>(&plds[r31][16 * ks + 8 * h]) = p0;
      *reinterpret_cast<float4*>(&plds[r31][16 * ks + 8 * h + 4]) = p1;
    }
    const float* anb = annot + (size_t)(R0 + r31) * ADim + 8 * h;
#pragma unroll
    for (int ks = 0; ks < 2; ++ks) {
      float4 a0 = *reinterpret_cast<const float4*>(anb + 16 * ks);
      float4 a1 = *reinterpret_cast<const float4*>(anb + 16 * ks + 4);
      xan[ks] = cvt8(a0, a1);
    }
  }
  __syncthreads();

#define LDWP(base, ks, oh) \
  (*reinterpret_cast<const bf16x8*>(Wp + (((size_t)(base) + (ks) * 2 + (oh)) * 64 + l) * 8))

  f32x16 aR[2] = {zero16(), zero16()}, aZ[2] = {zero16(), zero16()};
#pragma unroll
  for (int ks = 0; ks < 8; ++ks) {
    bf16x8 af = (ks < 4) ? xa[ks] : xp[ks - 4];
#pragma unroll
    for (int oh = 0; oh < 2; ++oh) {
      aR[oh] = mm(af, LDWP(0, ks, oh), aR[oh]);
      aZ[oh] = mm(af, LDWP(16, ks, oh), aZ[oh]);
    }
  }
  const float br_[2] = {br[r31], br[32 + r31]};
  const float bz_[2] = {bz[r31], bz[32 + r31]};
  float propv[2][16], zv[2][16];
#pragma unroll
  for (int oh = 0; oh < 2; ++oh) {
#pragma unroll
    for (int reg = 0; reg < 16; ++reg) {
      int row = (reg & 3) + 8 * (reg >> 2) + 4 * h;
      int o = 32 * oh + r31;
      propv[oh][reg] = plds[row][o];
      float rv = sigm(aR[oh][reg] + br_[oh]);
      zv[oh][reg] = sigm(aZ[oh][reg] + bz_[oh]);
      tlds[row][o] = rv * propv[oh][reg];
    }
  }
  __syncthreads();
  bf16x8 xr[4];
#pragma unroll
  for (int ks = 0; ks < 4; ++ks) {
    float4 t0 = *reinterpret_cast<const float4*>(&tlds[r31][16 * ks + 8 * h]);
    float4 t1 = *reinterpret_cast<const float4*>(&tlds[r31][16 * ks + 8 * h + 4]);
    xr[ks] = cvt8(t0, t1);
  }
  f32x16 aH[2] = {zero16(), zero16()};
#pragma unroll
  for (int ks = 0; ks < 8; ++ks) {
    bf16x8 af = (ks < 4) ? xa[ks] : xr[ks - 4];
#pragma unroll
    for (int oh = 0; oh < 2; ++oh) aH[oh] = mm(af, LDWP(32, ks, oh), aH[oh]);
  }
  __syncthreads();
  const float bh_[2] = {bh[r31], bh[32 + r31]};
#pragma unroll
  for (int oh = 0; oh < 2; ++oh) {
#pragma unroll
    for (int reg = 0; reg < 16; ++reg) {
      int row = (reg & 3) + 8 * (reg >> 2) + 4 * h;
      int o = 32 * oh + r31;
      float hh = tanh_fast(aH[oh][reg] + bh_[oh]);
      float z = zv[oh][reg];
      tlds[row][o] = (1.f - z) * propv[oh][reg] + z * hh;
    }
  }
  __syncthreads();
  bf16x8 xn[4];
#pragma unroll
  for (int ks = 0; ks < 4; ++ks) {
    float4 t0 = *reinterpret_cast<const float4*>(&tlds[r31][16 * ks + 8 * h]);
    float4 t1 = *reinterpret_cast<const float4*>(&tlds[r31][16 * ks + 8 * h + 4]);
    xn[ks] = cvt8(t0, t1);
  }
  f32x16 aO[2] = {zero16(), zero16()};
#pragma unroll
  for (int ks = 0; ks < 6; ++ks) {
    bf16x8 af = (ks < 4) ? xn[ks] : xan[ks - 4];
#pragma unroll
    for (int oh = 0; oh < 2; ++oh) aO[oh] = mm(af, LDWP(48, ks, oh), aO[oh]);
  }
  const float bo1_[2] = {bo1[r31], bo1[32 + r31]};
  const float wo2_[2] = {Wo2[r31], Wo2[32 + r31]};
  const float bo2v = bo2[0];
#pragma unroll
  for (int reg = 0; reg < 16; ++reg) {
    float h0 = tanh_fast(aO[0][reg] + bo1_[0]);
    float h1 = tanh_fast(aO[1][reg] + bo1_[1]);
    float p = h0 * wo2_[0] + h1 * wo2_[1];
#pragma unroll
    for (int mks = 16; mks >= 1; mks >>= 1) p += __shfl_xor(p, mks, 64);
    if (r31 == 0) {
      int row = (reg & 3) + 8 * (reg >> 2) + 4 * h;
      out[R0 + row] = p + bo2v;
    }
  }
#undef LDWP
}

extern "C" void kernel_launch(void* const* d_in, const int* in_sizes, int n_in,
                              void* d_out, int out_size, void* d_ws, size_t ws_size,
                              hipStream_t stream) {
  const float* prop  = (const float*)d_in[0];
  const float* annot = (const float*)d_in[1];
  const float* A     = (const float*)d_in[2];
  const float* Win   = (const float*)d_in[3];
  const float* bin   = (const float*)d_in[4];
  const float* Wr    = (const float*)d_in[5];
  const float* br    = (const float*)d_in[6];
  const float* Wz    = (const float*)d_in[7];
  const float* bz    = (const float*)d_in[8];
  const float* Wh    = (const float*)d_in[9];
  const float* bh    = (const float*)d_in[10];
  const float* Wo1   = (const float*)d_in[11];
  const float* bo1   = (const float*)d_in[12];
  const float* Wo2   = (const float*)d_in[13];
  const float* bo2   = (const float*)d_in[14];
  float* out = (float*)d_out;

  char* ws = (char*)d_ws;
  __bf16* Bt   = (__bf16*)ws;                              // [2][64][16384] bf16 = 4 MB
  float*  part = (float*)(ws + (size_t)4 * 1024 * 1024);   // [8][256][32][64] f32 = 16 MB
  __bf16* Wp   = (__bf16*)(ws + (size_t)20 * 1024 * 1024); // 60 KB

  k_pack<<<dim3(60), 64, 0, stream>>>(Wr, Wz, Wh, Wo1, Wp);
  k_build_bt<<<dim3(Nn / 64, Ee, Bz), 256, 0, stream>>>(prop, Win, bin, Bt);
  k_big_gemm<<<dim3(KSEG * NT), 512, 0, stream>>>(A, Bt, part);
  k_gru<<<dim3(NT), 64, 0, stream>>>(part, prop, annot, Wp,
                                     br, bz, bh, bo1, Wo2, bo2, out);
}